// Round 1
// baseline (330.303 us; speedup 1.0000x reference)
//
#include <hip/hip_runtime.h>
#include <hip/hip_bf16.h>

typedef __bf16 bf16_t;
typedef __bf16 bf16x8 __attribute__((ext_vector_type(8)));
typedef float  f32x4  __attribute__((ext_vector_type(4)));

#define DIM     1024
#define NHEAD   16
#define HDIM    64
#define NTIME   4
#define TSEQ    2048
#define NBATCH  2
#define MTOK    (NBATCH*TSEQ)   // 4096
#define SCALE_F 0.125f          // 64^-0.5

// ---------------- workspace layout (bytes) ----------------
#define OFF_WQKVT 0UL                                   // [3072][1024] bf16 (B^T, cols: Q(0..1023) K(1024..2047) V(2048..3071))
#define OFF_WOUTT (OFF_WQKVT + 3072UL*1024UL*2UL)       // [1024][1024] bf16 (B^T of Wout)
#define OFF_Q     (OFF_WOUTT + 1024UL*1024UL*2UL)       // [B][NH][T][HD] bf16
#define OFF_K     (OFF_Q  + 2UL*16UL*2048UL*64UL*2UL)   // [B][NH][T][HD] bf16
#define OFF_VT    (OFF_K  + 2UL*16UL*2048UL*64UL*2UL)   // [B][NH][HD][T] bf16 (V transposed)
#define OFF_CTX   (OFF_VT + 2UL*16UL*2048UL*64UL*2UL)   // [4096][1024] bf16
// total = 41,943,040 bytes

// ---------------- weight prep ----------------
__global__ void prep_wqkv(const float* __restrict__ Wqt, const float* __restrict__ Wkt,
                          const float* __restrict__ Wqs, const float* __restrict__ Wks,
                          const float* __restrict__ Wv,  bf16_t* __restrict__ WqkvT) {
    int idx = blockIdx.x * 256 + threadIdx.x;   // [0, 3072*1024)
    int c = idx >> 10;          // output column 0..3071
    int k = idx & 1023;         // reduction dim
    int region = c >> 10;       // 0=Q, 1=K, 2=V
    int cc = c & 1023;
    int h = cc >> 6, d = cc & 63;
    float v;
    if (region == 2) {
        v = Wv[(size_t)k * 1024 + cc];
    } else {
        const float* Wt = (region == 0) ? Wqt : Wkt;
        const float* Ws = (region == 0) ? Wqs : Wks;
        v = (h < NTIME) ? Wt[(size_t)k * (NTIME*HDIM) + h*HDIM + d]
                        : Ws[(size_t)k * ((NHEAD-NTIME)*HDIM) + (h-NTIME)*HDIM + d];
    }
    WqkvT[(size_t)c * 1024 + k] = (bf16_t)v;
}

__global__ void prep_wout(const float* __restrict__ Wout, bf16_t* __restrict__ WoutT) {
    int idx = blockIdx.x * 256 + threadIdx.x;   // [0, 1024*1024)
    int n = idx >> 10, k = idx & 1023;
    WoutT[(size_t)n * 1024 + k] = (bf16_t)Wout[(size_t)k * 1024 + n];  // Wout stored (in,out)
}

// ---------------- GEMM: C[M][N] = A[M][1024] * Bt[N][1024]^T ----------------
// MODE 0: A = x (f32, converted inline), epilogue scatters Q/K (row-major) and V (transposed), bf16
// MODE 1: A = ctx (bf16), epilogue writes f32 out + bias
template<int MODE>
__global__ __launch_bounds__(256)
void gemm_bf16(const float* __restrict__ Af, const bf16_t* __restrict__ Ab,
               const bf16_t* __restrict__ Bt,
               bf16_t* __restrict__ Qb, bf16_t* __restrict__ Kb, bf16_t* __restrict__ Vt,
               float* __restrict__ Cout, const float* __restrict__ bias)
{
    __shared__ __align__(16) bf16_t As[128][32];   // [m][k], 16B col-groups XOR-swizzled by (row&3)
    __shared__ __align__(16) bf16_t Bs[128][32];   // [n][k], same swizzle

    const int tid  = threadIdx.x;
    const int lane = tid & 63;
    const int wave = tid >> 6;
    const int wm = (wave >> 1) * 64, wn = (wave & 1) * 64;
    const int m0 = blockIdx.y * 128, n0 = blockIdx.x * 128;
    const int g = lane >> 4, lr = lane & 15;

    f32x4 acc[4][4];
#pragma unroll
    for (int i = 0; i < 4; ++i)
#pragma unroll
        for (int j = 0; j < 4; ++j) acc[i][j] = f32x4{0.f, 0.f, 0.f, 0.f};

    for (int k0 = 0; k0 < 1024; k0 += 32) {
        __syncthreads();   // protect LDS against previous iteration's readers
#pragma unroll
        for (int c = 0; c < 2; ++c) {
            int idx = tid + c * 256;          // 0..511 chunks of 8 bf16
            int row = idx >> 2;
            int cg  = idx & 3;
            int scg = cg ^ (row & 3);
            if constexpr (MODE == 0) {
                const float* s = Af + (size_t)(m0 + row) * 1024 + k0 + cg * 8;
                bf16x8 v;
#pragma unroll
                for (int e = 0; e < 8; ++e) v[e] = (bf16_t)s[e];
                *(bf16x8*)&As[row][scg * 8] = v;
            } else {
                *(bf16x8*)&As[row][scg * 8] =
                    *(const bf16x8*)(Ab + (size_t)(m0 + row) * 1024 + k0 + cg * 8);
            }
            *(bf16x8*)&Bs[row][scg * 8] =
                *(const bf16x8*)(Bt + (size_t)(n0 + row) * 1024 + k0 + cg * 8);
        }
        __syncthreads();

        bf16x8 afr[4], bfr[4];
#pragma unroll
        for (int f = 0; f < 4; ++f) {
            int ra = wm + f * 16 + lr;
            afr[f] = *(const bf16x8*)&As[ra][(g ^ (ra & 3)) * 8];
            int rb = wn + f * 16 + lr;
            bfr[f] = *(const bf16x8*)&Bs[rb][(g ^ (rb & 3)) * 8];
        }
#pragma unroll
        for (int fm = 0; fm < 4; ++fm)
#pragma unroll
            for (int fn = 0; fn < 4; ++fn)
                acc[fm][fn] = __builtin_amdgcn_mfma_f32_16x16x32_bf16(afr[fm], bfr[fn], acc[fm][fn], 0, 0, 0);
    }

    // epilogue: D-frag layout col = lane&15, row = (lane>>4)*4 + reg  [m89-verified]
#pragma unroll
    for (int fm = 0; fm < 4; ++fm) {
#pragma unroll
        for (int fn = 0; fn < 4; ++fn) {
#pragma unroll
            for (int r = 0; r < 4; ++r) {
                int m = m0 + wm + fm * 16 + g * 4 + r;
                int n = n0 + wn + fn * 16 + lr;
                float val = acc[fm][fn][r];
                if constexpr (MODE == 1) {
                    Cout[(size_t)m * DIM + n] = val + bias[n];
                } else {
                    int b = m >> 11, t = m & 2047;
                    int region = n >> 10, cc = n & 1023;
                    int h = cc >> 6, d = cc & 63;
                    bf16_t bv = (bf16_t)val;
                    size_t bh = (size_t)(b * NHEAD + h);
                    if (region == 0)      Qb[(bh * TSEQ + t) * HDIM + d] = bv;
                    else if (region == 1) Kb[(bh * TSEQ + t) * HDIM + d] = bv;
                    else                  Vt[(bh * HDIM + d) * TSEQ + t] = bv;  // transposed
                }
            }
        }
    }
}

// ---------------- flash attention ----------------
// one wave per (b, h, 16 q-rows); full softmax over T=2048 via online rescale
__global__ __launch_bounds__(64)
void attn_kernel(const bf16_t* __restrict__ Qb, const bf16_t* __restrict__ Kb,
                 const bf16_t* __restrict__ Vt, bf16_t* __restrict__ ctx,
                 const float* __restrict__ w_sigma)
{
    __shared__ __align__(16) bf16_t P_lds[16][32];

    const int bid = blockIdx.x;          // ((b*NH + h) * 128 + qt)
    const int qt  = bid & 127;
    const int bh  = bid >> 7;
    const int h   = bh & 15;
    const int b   = bh >> 4;
    const int q0  = qt * 16;
    const int lane = threadIdx.x;
    const int g = lane >> 4, lr = lane & 15;

    const float sig = 1.f / (1.f + __expf(-w_sigma[0]));
    const float factor = (h < NTIME) ? (-sig * SCALE_F) : SCALE_F;

    const bf16_t* Qp = Qb + (size_t)bh * TSEQ * HDIM;
    const bf16_t* Kp = Kb + (size_t)bh * TSEQ * HDIM;
    const bf16_t* Vp = Vt + (size_t)bh * HDIM * TSEQ;

    // Q fragments for this q-tile, kept in registers all block
    const bf16x8 qa0 = *(const bf16x8*)(Qp + (size_t)(q0 + lr) * HDIM + g * 8);
    const bf16x8 qa1 = *(const bf16x8*)(Qp + (size_t)(q0 + lr) * HDIM + 32 + g * 8);

    f32x4 o[4];
#pragma unroll
    for (int n = 0; n < 4; ++n) o[n] = f32x4{0.f, 0.f, 0.f, 0.f};
    float mrun[4] = {-1e30f, -1e30f, -1e30f, -1e30f};
    float lrun[4] = {0.f, 0.f, 0.f, 0.f};

    for (int s0 = 0; s0 < TSEQ; s0 += 32) {
        // ---- S = Q K^T for two 16-wide s-subtiles (K over HD=64 in 2 steps) ----
        f32x4 sfr[2];
#pragma unroll
        for (int st = 0; st < 2; ++st) {
            const int sb = s0 + st * 16;
            bf16x8 kb0 = *(const bf16x8*)(Kp + (size_t)(sb + lr) * HDIM + g * 8);
            bf16x8 kb1 = *(const bf16x8*)(Kp + (size_t)(sb + lr) * HDIM + 32 + g * 8);
            f32x4 z = f32x4{0.f, 0.f, 0.f, 0.f};
            z = __builtin_amdgcn_mfma_f32_16x16x32_bf16(qa0, kb0, z, 0, 0, 0);
            z = __builtin_amdgcn_mfma_f32_16x16x32_bf16(qa1, kb1, z, 0, 0, 0);
            sfr[st] = z;
        }

        // ---- online softmax (per D-frag row = g*4+r; reduce across 16 lanes of group) ----
        float alpha[4];
#pragma unroll
        for (int r = 0; r < 4; ++r) {
            float sv0 = sfr[0][r] * factor;
            float sv1 = sfr[1][r] * factor;
            float pm = fmaxf(sv0, sv1);
#pragma unroll
            for (int msk = 1; msk < 16; msk <<= 1) pm = fmaxf(pm, __shfl_xor(pm, msk, 64));
            float mn = fmaxf(mrun[r], pm);
            float a = __expf(mrun[r] - mn);
            mrun[r] = mn;
            float p0 = __expf(sv0 - mn);
            float p1 = __expf(sv1 - mn);
            float rs = p0 + p1;
#pragma unroll
            for (int msk = 1; msk < 16; msk <<= 1) rs += __shfl_xor(rs, msk, 64);
            lrun[r] = lrun[r] * a + rs;
            alpha[r] = a;
            // store P (bf16) swizzled: col = st*16+lr, slot = (col>>3) ^ (row&3)
            int row = g * 4 + r;
            P_lds[row][(((lr >> 3)     ) ^ (row & 3)) * 8 + (lr & 7)] = (bf16_t)p0;
            P_lds[row][(((lr >> 3) + 2 ) ^ (row & 3)) * 8 + (lr & 7)] = (bf16_t)p1;
        }
#pragma unroll
        for (int n = 0; n < 4; ++n) {
#pragma unroll
            for (int r = 0; r < 4; ++r) o[n][r] *= alpha[r];
        }
        __syncthreads();   // P_lds RAW (cross-lane); 1-wave block -> cheap

        // ---- O += P * V  (A = P rows q, B = V^T rows d) ----
        bf16x8 pa = *(const bf16x8*)&P_lds[lr][(g ^ (lr & 3)) * 8];
#pragma unroll
        for (int n = 0; n < 4; ++n) {
            bf16x8 vb = *(const bf16x8*)(Vp + (size_t)(n * 16 + lr) * TSEQ + s0 + g * 8);
            o[n] = __builtin_amdgcn_mfma_f32_16x16x32_bf16(pa, vb, o[n], 0, 0, 0);
        }
        __syncthreads();   // P_lds WAR before next iteration's writes
    }

    // ---- finalize: ctx[b][t][h*64 + d], bf16 ----
#pragma unroll
    for (int n = 0; n < 4; ++n) {
#pragma unroll
        for (int r = 0; r < 4; ++r) {
            float val = o[n][r] / lrun[r];
            int t = q0 + g * 4 + r;
            ctx[((size_t)(b * TSEQ + t)) * DIM + h * HDIM + n * 16 + lr] = (bf16_t)val;
        }
    }
}

// ---------------- launch ----------------
extern "C" void kernel_launch(void* const* d_in, const int* in_sizes, int n_in,
                              void* d_out, int out_size, void* d_ws, size_t ws_size,
                              hipStream_t stream) {
    const float* x    = (const float*)d_in[0];
    const float* Wqt  = (const float*)d_in[1];
    const float* Wkt  = (const float*)d_in[2];
    const float* Wqs  = (const float*)d_in[3];
    const float* Wks  = (const float*)d_in[4];
    const float* Wv   = (const float*)d_in[5];
    const float* Wout = (const float*)d_in[6];
    const float* bout = (const float*)d_in[7];
    const float* wsig = (const float*)d_in[8];
    (void)in_sizes; (void)n_in; (void)out_size; (void)ws_size;

    char* ws = (char*)d_ws;
    bf16_t* WqkvT = (bf16_t*)(ws + OFF_WQKVT);
    bf16_t* WoutT = (bf16_t*)(ws + OFF_WOUTT);
    bf16_t* Qb    = (bf16_t*)(ws + OFF_Q);
    bf16_t* Kb    = (bf16_t*)(ws + OFF_K);
    bf16_t* Vt    = (bf16_t*)(ws + OFF_VT);
    bf16_t* ctx   = (bf16_t*)(ws + OFF_CTX);
    float*  out   = (float*)d_out;

    prep_wqkv<<<12288, 256, 0, stream>>>(Wqt, Wkt, Wqs, Wks, Wv, WqkvT);
    prep_wout<<<4096, 256, 0, stream>>>(Wout, WoutT);

    // x @ Wqkv -> Q, K (row-major), V (transposed), all bf16
    gemm_bf16<0><<<dim3(24, 32), 256, 0, stream>>>(x, nullptr, WqkvT, Qb, Kb, Vt, nullptr, nullptr);

    // attention
    attn_kernel<<<NBATCH * NHEAD * (TSEQ / 16), 64, 0, stream>>>(Qb, Kb, Vt, ctx, wsig);

    // ctx @ Wout + bout -> f32 out
    gemm_bf16<1><<<dim3(8, 32), 256, 0, stream>>>(nullptr, ctx, WoutT, nullptr, nullptr, nullptr, out, bout);
}